// Round 1
// baseline (174.852 us; speedup 1.0000x reference)
//
#include <hip/hip_runtime.h>

#define BATCH 32
#define CH    84
#define NA    8400
#define KTOP  1000
#define MAXC  512            // cap on candidates/image (expected ~105, sigma ~10)
#define NW    (MAXC/64)      // 8 bitmask words per row
#define GROUPS 2100          // NA/4 float4 groups per image
#define SLICES 9             // ceil(2100/256)

// ---------------- Kernel A: candidate detection ----------------
// valid anchor: s0 > 0.1 && s0 >= max(s1..s79)  (== argmax over 80 classes is 0 && conf>0.1)
__global__ __launch_bounds__(256) void cand_kernel(const float* __restrict__ preds,
        int* __restrict__ counts, float* __restrict__ cscore, int* __restrict__ cidx) {
    int blk = blockIdx.x;
    int b = blk / SLICES;
    int slice = blk - b * SLICES;
    int g = slice * 256 + threadIdx.x;   // group of 4 anchors

    __shared__ int lcount;
    __shared__ int lbase;
    __shared__ float lsc[1024];
    __shared__ int   lix[1024];
    if (threadIdx.x == 0) lcount = 0;
    __syncthreads();

    if (g < GROUPS) {
        const float* base = preds + (size_t)b * (CH * NA);
        const float4 s0 = *(const float4*)(base + 4 * NA + 4 * g);   // class 0 scores
        float4 m; m.x = m.y = m.z = m.w = -1.0f;
        #pragma unroll 4
        for (int c = 5; c < CH; ++c) {
            float4 v = *(const float4*)(base + c * NA + 4 * g);
            m.x = fmaxf(m.x, v.x);
            m.y = fmaxf(m.y, v.y);
            m.z = fmaxf(m.z, v.z);
            m.w = fmaxf(m.w, v.w);
        }
        float s[4]  = {s0.x, s0.y, s0.z, s0.w};
        float mm[4] = {m.x, m.y, m.z, m.w};
        #pragma unroll
        for (int k = 0; k < 4; ++k) {
            if (s[k] > 0.1f && s[k] >= mm[k]) {
                int p = atomicAdd(&lcount, 1);
                lsc[p] = s[k];
                lix[p] = 4 * g + k;
            }
        }
    }
    __syncthreads();
    if (threadIdx.x == 0) lbase = atomicAdd(&counts[b], lcount);
    __syncthreads();
    int n = lcount, bs = lbase;
    for (int i = threadIdx.x; i < n; i += 256) {
        int p = bs + i;
        if (p < MAXC) {
            cscore[b * MAXC + p] = lsc[i];
            cidx[b * MAXC + p]   = lix[i];
        }
    }
}

// ---------------- Kernel B: sort + NMS + output ----------------
__global__ __launch_bounds__(256) void nms_kernel(const float* __restrict__ preds,
        const int* __restrict__ counts, const float* __restrict__ cscore,
        const int* __restrict__ cidx, float* __restrict__ out) {
    int b = blockIdx.x;
    int tid = threadIdx.x;

    __shared__ float rs[MAXC]; __shared__ int ri[MAXC];   // raw candidates
    __shared__ float ss[MAXC]; __shared__ int sa[MAXC];   // sorted by (score desc, idx asc)
    __shared__ float x1[MAXC], y1[MAXC], x2[MAXC], y2[MAXC], ar[MAXC];
    __shared__ unsigned long long mask[MAXC][NW];         // 32 KiB suppression matrix
    __shared__ unsigned long long keepw[NW];

    int n = counts[b];
    if (n > MAXC) n = MAXC;

    for (int i = tid; i < n; i += 256) { rs[i] = cscore[b * MAXC + i]; ri[i] = cidx[b * MAXC + i]; }
    __syncthreads();

    // stable rank sort: rank = #{j : s_j > s_i || (s_j == s_i && idx_j < idx_i)}
    for (int i = tid; i < n; i += 256) {
        float si = rs[i]; int ii = ri[i];
        int r = 0;
        for (int j = 0; j < n; ++j) {
            float sj = rs[j]; int ij = ri[j];
            if (sj > si || (sj == si && ij < ii)) r++;
        }
        ss[r] = si; sa[r] = ii;
    }
    __syncthreads();

    // gather boxes, xywh -> xyxy
    const float* base = preds + (size_t)b * (CH * NA);
    for (int i = tid; i < n; i += 256) {
        int a = sa[i];
        float cx = base[0 * NA + a], cy = base[1 * NA + a];
        float w  = base[2 * NA + a], h  = base[3 * NA + a];
        float hx = w * 0.5f, hy = h * 0.5f;
        float X1 = cx - hx, Y1 = cy - hy, X2 = cx + hx, Y2 = cy + hy;
        x1[i] = X1; y1[i] = Y1; x2[i] = X2; y2[i] = Y2;
        ar[i] = (X2 - X1) * (Y2 - Y1);
    }
    __syncthreads();

    // pairwise suppression bitmask: mask[i][w] bit (j-64w) set iff j>i && iou(i,j)>0.7
    int nw = (n + 63) >> 6;
    for (int t = tid; t < n * nw; t += 256) {
        int i = t / nw;
        int w = t - i * nw;
        int j0 = w * 64;
        int jend = (j0 + 64 < n) ? (j0 + 64) : n;
        int jstart = (j0 > i + 1) ? j0 : (i + 1);
        unsigned long long bits = 0ull;
        float xi1 = x1[i], yi1 = y1[i], xi2 = x2[i], yi2 = y2[i], ai = ar[i];
        for (int j = jstart; j < jend; ++j) {
            float lx = fmaxf(xi1, x1[j]), ly = fmaxf(yi1, y1[j]);
            float rx = fminf(xi2, x2[j]), ry = fminf(yi2, y2[j]);
            float iw = fmaxf(rx - lx, 0.0f), ih = fmaxf(ry - ly, 0.0f);
            float inter = iw * ih;
            float iou = inter / (ai + ar[j] - inter + 1e-7f);
            if (iou > 0.7f) bits |= (1ull << (j - j0));
        }
        mask[i][w] = bits;
    }
    __syncthreads();

    // serial greedy scan over bitmask words (thread 0; ~n iters, few words each)
    if (tid == 0) {
        unsigned long long kp[NW];
        #pragma unroll
        for (int w = 0; w < NW; ++w) {
            int lo = w * 64;
            if (n >= lo + 64)      kp[w] = ~0ull;
            else if (n <= lo)      kp[w] = 0ull;
            else                   kp[w] = (1ull << (n - lo)) - 1ull;
        }
        for (int i = 0; i < n; ++i) {
            if ((kp[i >> 6] >> (i & 63)) & 1ull) {
                for (int w = (i >> 6); w < nw; ++w) kp[w] &= ~mask[i][w];
            }
        }
        #pragma unroll
        for (int w = 0; w < NW; ++w) keepw[w] = kp[w];
    }
    __syncthreads();

    // write all K rows (d_out is poisoned -> zeros must be written too)
    float* ob = out + (size_t)b * KTOP * 6;
    const float SCALE = (float)(640.0 / 1920.0);
    for (int r = tid; r < KTOP; r += 256) {
        float v0 = 0.f, v1 = 0.f, v2 = 0.f, v3 = 0.f, v4 = 0.f, v5 = 0.f;
        if (r < n && ((keepw[r >> 6] >> (r & 63)) & 1ull)) {
            v0 = x1[r] / SCALE; v1 = y1[r] / SCALE;
            v2 = x2[r] / SCALE; v3 = y2[r] / SCALE;
            v4 = ss[r]; v5 = 0.0f;
        }
        ob[r * 6 + 0] = v0; ob[r * 6 + 1] = v1; ob[r * 6 + 2] = v2;
        ob[r * 6 + 3] = v3; ob[r * 6 + 4] = v4; ob[r * 6 + 5] = v5;
    }
}

extern "C" void kernel_launch(void* const* d_in, const int* in_sizes, int n_in,
                              void* d_out, int out_size, void* d_ws, size_t ws_size,
                              hipStream_t stream) {
    const float* preds = (const float*)d_in[0];
    float* out = (float*)d_out;

    int*   counts = (int*)d_ws;
    float* cscore = (float*)((char*)d_ws + 128);
    int*   cidx   = (int*)((char*)d_ws + 128 + (size_t)BATCH * MAXC * sizeof(float));

    hipMemsetAsync(d_ws, 0, 128, stream);  // zero per-image counts (ws is poisoned)
    cand_kernel<<<BATCH * SLICES, 256, 0, stream>>>(preds, counts, cscore, cidx);
    nms_kernel<<<BATCH, 256, 0, stream>>>(preds, counts, cscore, cidx, out);
}

// Round 2
// 172.309 us; speedup vs baseline: 1.0148x; 1.0148x over previous
//
#include <hip/hip_runtime.h>

#define BATCH 32
#define CH    84
#define NA    8400
#define KTOP  1000
#define MAXC  512            // cap on candidates/image (expected ~105, sigma ~10)
#define GROUPS 2100          // NA/4 float4 groups per image
#define SLICES 33            // ceil(2100/64) groups-per-block=64
#define IOU_T 0.7f

// ---------------- Kernel A: candidate detection ----------------
// 4 threads per float4 anchor-group; each thread scans ~20 of the 79 competitor
// channels (5..83), quad-reduce via shfl_xor, lane (t&3)==0 tests class-0 score.
// valid anchor: s0 > 0.1 && s0 >= max(s1..s79)
__global__ __launch_bounds__(256) void cand_kernel(const float* __restrict__ preds,
        int* __restrict__ counts, float* __restrict__ cscore, int* __restrict__ cidx) {
    int b = blockIdx.x / SLICES;
    int slice = blockIdx.x - b * SLICES;
    int t = threadIdx.x;
    int gl = t >> 2, chunk = t & 3;
    int g = slice * 64 + gl;             // anchor group 0..2099
    bool active = g < GROUPS;

    __shared__ int lcount, lbase;
    __shared__ float lsc[256];
    __shared__ int   lix[256];
    if (t == 0) lcount = 0;
    __syncthreads();

    const float* base = preds + (size_t)b * (CH * NA);
    float mx = -1.f, my = -1.f, mz = -1.f, mw = -1.f;
    if (active) {
        int c0 = 5 + chunk * 20;
        int c1 = (chunk == 3) ? CH : c0 + 20;   // chunk3 covers 65..83 (19 ch)
        const float* p = base + (size_t)c0 * NA + 4 * g;
        for (int c = c0; c < c1; ++c, p += NA) {
            float4 v = *(const float4*)p;
            mx = fmaxf(mx, v.x); my = fmaxf(my, v.y);
            mz = fmaxf(mz, v.z); mw = fmaxf(mw, v.w);
        }
    }
    // reduce max over the 4 chunk lanes (adjacent lanes, same group)
    mx = fmaxf(mx, __shfl_xor(mx, 1)); my = fmaxf(my, __shfl_xor(my, 1));
    mz = fmaxf(mz, __shfl_xor(mz, 1)); mw = fmaxf(mw, __shfl_xor(mw, 1));
    mx = fmaxf(mx, __shfl_xor(mx, 2)); my = fmaxf(my, __shfl_xor(my, 2));
    mz = fmaxf(mz, __shfl_xor(mz, 2)); mw = fmaxf(mw, __shfl_xor(mw, 2));

    if (active && chunk == 0) {
        float4 s0 = *(const float4*)(base + (size_t)4 * NA + 4 * g);
        float s[4] = {s0.x, s0.y, s0.z, s0.w};
        float m[4] = {mx, my, mz, mw};
        #pragma unroll
        for (int k = 0; k < 4; ++k) {
            if (s[k] > 0.1f && s[k] >= m[k]) {
                int p_ = atomicAdd(&lcount, 1);
                lsc[p_] = s[k];
                lix[p_] = 4 * g + k;
            }
        }
    }
    __syncthreads();
    if (t == 0) lbase = atomicAdd(&counts[b], lcount);
    __syncthreads();
    int nloc = lcount, bs = lbase;
    for (int i = t; i < nloc; i += 256) {
        int p_ = bs + i;
        if (p_ < MAXC) {
            cscore[b * MAXC + p_] = lsc[i];
            cidx[b * MAXC + p_]   = lix[i];
        }
    }
}

// ---------------- wave-parallel greedy NMS scan ----------------
// One wave (64 lanes); lane owns candidates k*64+lane, k<S, boxes in NAMED regs
// (compile-time indexed -> no scratch). Suppressor i's keep bit via __ballot,
// its box via same-address LDS broadcast. Returns per-lane keep bitmask.
template<int S>
__device__ unsigned int nms_scan(int n, int lane, const float4* bxy, const float* ars) {
    float ox1[S], oy1[S], ox2[S], oy2[S], oar[S];
    unsigned int keep = 0u;
    #pragma unroll
    for (int k = 0; k < S; ++k) {
        int c = k * 64 + lane;
        if (c < n) {
            float4 v = bxy[c];
            ox1[k] = v.x; oy1[k] = v.y; ox2[k] = v.z; oy2[k] = v.w;
            oar[k] = ars[c];
            keep |= (1u << k);
        } else {
            ox1[k] = 0.f; oy1[k] = 0.f; ox2[k] = -1.f; oy2[k] = -1.f; oar[k] = 0.f;
        }
    }
    for (int i = 0; i < n; ++i) {
        int which = i >> 6, src = i & 63;
        int mybit = (keep >> which) & 1;
        unsigned long long bal = __ballot(mybit);
        if ((bal >> src) & 1ull) {          // uniform branch: is candidate i kept?
            float4 bi = bxy[i];             // LDS broadcast (same address all lanes)
            float ai = ars[i];
            #pragma unroll
            for (int k = 0; k < S; ++k) {
                float lx = fmaxf(bi.x, ox1[k]), ly = fmaxf(bi.y, oy1[k]);
                float rx = fminf(bi.z, ox2[k]), ry = fminf(bi.w, oy2[k]);
                float iw = fmaxf(rx - lx, 0.0f), ih = fmaxf(ry - ly, 0.0f);
                float inter = iw * ih;
                float iou = inter / (ai + oar[k] - inter + 1e-7f);
                int c = k * 64 + lane;
                if (c > i && iou > IOU_T) keep &= ~(1u << k);
            }
        }
    }
    return keep;
}

// ---------------- Kernel B: sort + NMS + output ----------------
__global__ __launch_bounds__(256) void nms_kernel(const float* __restrict__ preds,
        const int* __restrict__ counts, const float* __restrict__ cscore,
        const int* __restrict__ cidx, float* __restrict__ out) {
    int b = blockIdx.x;
    int tid = threadIdx.x;

    __shared__ float rs[MAXC]; __shared__ int ri[MAXC];   // raw candidates
    __shared__ float ss[MAXC]; __shared__ int sa[MAXC];   // sorted (score desc, idx asc)
    __shared__ float4 bxy[MAXC];                          // sorted boxes xyxy
    __shared__ float  ars[MAXC];                          // areas
    __shared__ unsigned int keepm[64];                    // per-lane keep bitmask

    int n = counts[b];
    if (n > MAXC) n = MAXC;

    for (int i = tid; i < n; i += 256) { rs[i] = cscore[b * MAXC + i]; ri[i] = cidx[b * MAXC + i]; }
    __syncthreads();

    // stable rank sort: rank = #{j : s_j > s_i || (s_j == s_i && idx_j < idx_i)}
    for (int i = tid; i < n; i += 256) {
        float si = rs[i]; int ii = ri[i];
        int r = 0;
        for (int j = 0; j < n; ++j) {
            float sj = rs[j]; int ij = ri[j];
            if (sj > si || (sj == si && ij < ii)) r++;
        }
        ss[r] = si; sa[r] = ii;
    }
    __syncthreads();

    // gather boxes, xywh -> xyxy
    const float* base = preds + (size_t)b * (CH * NA);
    for (int i = tid; i < n; i += 256) {
        int a = sa[i];
        float cx = base[a], cy = base[NA + a];
        float w  = base[2 * NA + a], h = base[3 * NA + a];
        float hx = w * 0.5f, hy = h * 0.5f;
        float X1 = cx - hx, Y1 = cy - hy, X2 = cx + hx, Y2 = cy + hy;
        bxy[i] = make_float4(X1, Y1, X2, Y2);
        ars[i] = (X2 - X1) * (Y2 - Y1);
    }
    __syncthreads();

    if (tid < 64) {
        unsigned int kp;
        if (n <= 128)      kp = nms_scan<2>(n, tid, bxy, ars);
        else if (n <= 256) kp = nms_scan<4>(n, tid, bxy, ars);
        else               kp = nms_scan<8>(n, tid, bxy, ars);
        keepm[tid] = kp;
    }
    __syncthreads();

    // write all K rows (d_out is poisoned -> zeros must be written too)
    float* ob = out + (size_t)b * KTOP * 6;
    const float SCALEF = (float)(640.0 / 1920.0);
    for (int r = tid; r < KTOP; r += 256) {
        float v0 = 0.f, v1 = 0.f, v2 = 0.f, v3 = 0.f, v4 = 0.f, v5 = 0.f;
        if (r < n && ((keepm[r & 63] >> (r >> 6)) & 1u)) {
            float4 bx = bxy[r];
            v0 = bx.x / SCALEF; v1 = bx.y / SCALEF;
            v2 = bx.z / SCALEF; v3 = bx.w / SCALEF;
            v4 = ss[r]; v5 = 0.0f;
        }
        ob[r * 6 + 0] = v0; ob[r * 6 + 1] = v1; ob[r * 6 + 2] = v2;
        ob[r * 6 + 3] = v3; ob[r * 6 + 4] = v4; ob[r * 6 + 5] = v5;
    }
}

extern "C" void kernel_launch(void* const* d_in, const int* in_sizes, int n_in,
                              void* d_out, int out_size, void* d_ws, size_t ws_size,
                              hipStream_t stream) {
    const float* preds = (const float*)d_in[0];
    float* out = (float*)d_out;

    int*   counts = (int*)d_ws;
    float* cscore = (float*)((char*)d_ws + 128);
    int*   cidx   = (int*)((char*)d_ws + 128 + (size_t)BATCH * MAXC * sizeof(float));

    hipMemsetAsync(d_ws, 0, 128, stream);  // zero per-image counts (ws is poisoned)
    cand_kernel<<<BATCH * SLICES, 256, 0, stream>>>(preds, counts, cscore, cidx);
    nms_kernel<<<BATCH, 256, 0, stream>>>(preds, counts, cscore, cidx, out);
}

// Round 3
// 168.235 us; speedup vs baseline: 1.0393x; 1.0242x over previous
//
#include <hip/hip_runtime.h>

#define BATCH 32
#define CH    84
#define NA    8400
#define KTOP  1000
#define GROUPS 2100          // NA/4 float4 groups per image
#define SLICES 33            // ceil(2100/64); 64 groups (256 anchors) per block
#define SLOT   32            // max candidates stored per slice (expected ~3.2)
#define MAXC   (SLICES*SLOT) // 1056 candidate slots per image
#define IOU_T 0.7f

// ---------------- Kernel A: candidate detection ----------------
// 4 threads per float4 anchor-group; each thread scans 20 of the competitor
// channels (constant trip count; chunk3 overlaps ch 64 -- max is idempotent),
// quad-reduce via shfl_xor, lane (t&3)==0 tests class-0 score.
// valid anchor: s0 > 0.1 && s0 >= max(s1..s79)
// Output: per-slice slot lists + unconditional per-slice count (no memset,
// no global atomics; stream order makes writes visible to nms_kernel).
__global__ __launch_bounds__(256) void cand_kernel(const float* __restrict__ preds,
        int* __restrict__ counts, float* __restrict__ cscore, int* __restrict__ cidx) {
    int b = blockIdx.x / SLICES;
    int slice = blockIdx.x - b * SLICES;
    int t = threadIdx.x;
    int gl = t >> 2, chunk = t & 3;
    int g = slice * 64 + gl;             // anchor group 0..2099
    bool active = g < GROUPS;

    __shared__ int lcount;
    __shared__ float lsc[256];
    __shared__ int   lix[256];
    if (t == 0) lcount = 0;
    __syncthreads();

    const float* base = preds + (size_t)b * (CH * NA);
    float mx = -1.f, my = -1.f, mz = -1.f, mw = -1.f;
    if (active) {
        int c0 = (chunk < 3) ? (5 + 20 * chunk) : 64;   // 5..24,25..44,45..64,64..83
        const float* p = base + (size_t)c0 * NA + 4 * g;
        #pragma unroll 5
        for (int k = 0; k < 20; ++k, p += NA) {
            float4 v = *(const float4*)p;
            mx = fmaxf(mx, v.x); my = fmaxf(my, v.y);
            mz = fmaxf(mz, v.z); mw = fmaxf(mw, v.w);
        }
    }
    // reduce max over the 4 chunk lanes (adjacent lanes, same group)
    mx = fmaxf(mx, __shfl_xor(mx, 1)); my = fmaxf(my, __shfl_xor(my, 1));
    mz = fmaxf(mz, __shfl_xor(mz, 1)); mw = fmaxf(mw, __shfl_xor(mw, 1));
    mx = fmaxf(mx, __shfl_xor(mx, 2)); my = fmaxf(my, __shfl_xor(my, 2));
    mz = fmaxf(mz, __shfl_xor(mz, 2)); mw = fmaxf(mw, __shfl_xor(mw, 2));

    if (active && chunk == 0) {
        float4 s0 = *(const float4*)(base + (size_t)4 * NA + 4 * g);
        float s[4] = {s0.x, s0.y, s0.z, s0.w};
        float m[4] = {mx, my, mz, mw};
        #pragma unroll
        for (int k = 0; k < 4; ++k) {
            if (s[k] > 0.1f && s[k] >= m[k]) {
                int p_ = atomicAdd(&lcount, 1);     // LDS atomic only
                lsc[p_] = s[k];
                lix[p_] = 4 * g + k;
            }
        }
    }
    __syncthreads();
    int n = lcount; if (n > SLOT) n = SLOT;
    if (t == 0) counts[b * SLICES + slice] = n;      // unconditional: poison-proof
    if (t < n) {
        cscore[b * MAXC + slice * SLOT + t] = lsc[t];
        cidx[b * MAXC + slice * SLOT + t]   = lix[t];
    }
}

// ---------------- wave-parallel greedy NMS scan ----------------
// One wave (64 lanes); lane owns candidates k*64+lane, k<S, boxes in NAMED regs
// (compile-time indexed -> no scratch). Suppressor i's keep bit via __ballot,
// its box via same-address LDS broadcast. Returns per-lane keep bitmask.
template<int S>
__device__ unsigned int nms_scan(int n, int lane, const float4* bxy, const float* ars) {
    float ox1[S], oy1[S], ox2[S], oy2[S], oar[S];
    unsigned int keep = 0u;
    #pragma unroll
    for (int k = 0; k < S; ++k) {
        int c = k * 64 + lane;
        if (c < n) {
            float4 v = bxy[c];
            ox1[k] = v.x; oy1[k] = v.y; ox2[k] = v.z; oy2[k] = v.w;
            oar[k] = ars[c];
            keep |= (1u << k);
        } else {
            ox1[k] = 0.f; oy1[k] = 0.f; ox2[k] = -1.f; oy2[k] = -1.f; oar[k] = 0.f;
        }
    }
    for (int i = 0; i < n; ++i) {
        int which = i >> 6, src = i & 63;
        int mybit = (keep >> which) & 1;
        unsigned long long bal = __ballot(mybit);
        if ((bal >> src) & 1ull) {          // uniform branch: is candidate i kept?
            float4 bi = bxy[i];             // LDS broadcast (same address all lanes)
            float ai = ars[i];
            #pragma unroll
            for (int k = 0; k < S; ++k) {
                float lx = fmaxf(bi.x, ox1[k]), ly = fmaxf(bi.y, oy1[k]);
                float rx = fminf(bi.z, ox2[k]), ry = fminf(bi.w, oy2[k]);
                float iw = fmaxf(rx - lx, 0.0f), ih = fmaxf(ry - ly, 0.0f);
                float inter = iw * ih;
                float iou = inter / (ai + oar[k] - inter + 1e-7f);
                int c = k * 64 + lane;
                if (c > i && iou > IOU_T) keep &= ~(1u << k);
            }
        }
    }
    return keep;
}

// ---------------- Kernel B: compact + sort + NMS + output ----------------
__global__ __launch_bounds__(256) void nms_kernel(const float* __restrict__ preds,
        const int* __restrict__ counts, const float* __restrict__ cscore,
        const int* __restrict__ cidx, float* __restrict__ out) {
    int b = blockIdx.x;
    int tid = threadIdx.x;

    __shared__ int scnt[SLICES], soff[SLICES + 1];
    __shared__ float rs[MAXC]; __shared__ int ri[MAXC];   // compacted raw candidates
    __shared__ float ss[MAXC]; __shared__ int sa[MAXC];   // sorted (score desc, idx asc)
    __shared__ float4 bxy[MAXC];                          // sorted boxes xyxy
    __shared__ float  ars[MAXC];                          // areas
    __shared__ unsigned int keepm[64];                    // per-lane keep bitmask

    if (tid < SLICES) scnt[tid] = counts[b * SLICES + tid];
    __syncthreads();
    if (tid == 0) {                                       // 33-entry prefix sum, trivial
        int acc = 0;
        #pragma unroll
        for (int s_ = 0; s_ < SLICES; ++s_) { soff[s_] = acc; acc += scnt[s_]; }
        soff[SLICES] = acc;
    }
    __syncthreads();
    int n = soff[SLICES];

    // compact per-slice slots into dense [0,n)
    for (int t = tid; t < SLICES * SLOT; t += 256) {
        int slice = t >> 5, j = t & (SLOT - 1);
        if (j < scnt[slice]) {
            int dst = soff[slice] + j;
            rs[dst] = cscore[b * MAXC + t];
            ri[dst] = cidx[b * MAXC + t];
        }
    }
    __syncthreads();

    // stable rank sort: rank = #{j : s_j > s_i || (s_j == s_i && idx_j < idx_i)}
    for (int i = tid; i < n; i += 256) {
        float si = rs[i]; int ii = ri[i];
        int r = 0;
        for (int j = 0; j < n; ++j) {
            float sj = rs[j]; int ij = ri[j];
            if (sj > si || (sj == si && ij < ii)) r++;
        }
        ss[r] = si; sa[r] = ii;
    }
    __syncthreads();

    // gather boxes, xywh -> xyxy
    const float* base = preds + (size_t)b * (CH * NA);
    for (int i = tid; i < n; i += 256) {
        int a = sa[i];
        float cx = base[a], cy = base[NA + a];
        float w  = base[2 * NA + a], h = base[3 * NA + a];
        float hx = w * 0.5f, hy = h * 0.5f;
        float X1 = cx - hx, Y1 = cy - hy, X2 = cx + hx, Y2 = cy + hy;
        bxy[i] = make_float4(X1, Y1, X2, Y2);
        ars[i] = (X2 - X1) * (Y2 - Y1);
    }
    __syncthreads();

    if (tid < 64) {
        unsigned int kp;
        if (n <= 128)      kp = nms_scan<2>(n, tid, bxy, ars);
        else if (n <= 256) kp = nms_scan<4>(n, tid, bxy, ars);
        else if (n <= 512) kp = nms_scan<8>(n, tid, bxy, ars);
        else               kp = nms_scan<17>(n, tid, bxy, ars);  // up to 1088 >= MAXC
        keepm[tid] = kp;
    }
    __syncthreads();

    // write all K rows (d_out is poisoned -> zeros must be written too)
    float* ob = out + (size_t)b * KTOP * 6;
    const float SCALEF = (float)(640.0 / 1920.0);
    for (int r = tid; r < KTOP; r += 256) {
        float v0 = 0.f, v1 = 0.f, v2 = 0.f, v3 = 0.f, v4 = 0.f, v5 = 0.f;
        if (r < n && ((keepm[r & 63] >> (r >> 6)) & 1u)) {
            float4 bx = bxy[r];
            v0 = bx.x / SCALEF; v1 = bx.y / SCALEF;
            v2 = bx.z / SCALEF; v3 = bx.w / SCALEF;
            v4 = ss[r]; v5 = 0.0f;
        }
        ob[r * 6 + 0] = v0; ob[r * 6 + 1] = v1; ob[r * 6 + 2] = v2;
        ob[r * 6 + 3] = v3; ob[r * 6 + 4] = v4; ob[r * 6 + 5] = v5;
    }
}

extern "C" void kernel_launch(void* const* d_in, const int* in_sizes, int n_in,
                              void* d_out, int out_size, void* d_ws, size_t ws_size,
                              hipStream_t stream) {
    const float* preds = (const float*)d_in[0];
    float* out = (float*)d_out;

    // ws layout (all read locations are written by cand_kernel first -> no memset)
    int*   counts = (int*)d_ws;                                   // 32*33 ints
    float* cscore = (float*)((char*)d_ws + 16384);                // 32*1056 floats
    int*   cidx   = (int*)((char*)d_ws + 16384 + (size_t)BATCH * MAXC * sizeof(float));

    cand_kernel<<<BATCH * SLICES, 256, 0, stream>>>(preds, counts, cscore, cidx);
    nms_kernel<<<BATCH, 256, 0, stream>>>(preds, counts, cscore, cidx, out);
}

// Round 4
// 167.910 us; speedup vs baseline: 1.0413x; 1.0019x over previous
//
#include <hip/hip_runtime.h>

#define BATCH 32
#define CH    84
#define NA    8400
#define KTOP  1000
#define GROUPS 2100          // NA/4 float4 groups per image
#define SLICES 33            // ceil(2100/64); 64 groups (256 anchors) per block
#define SLOT   32            // max candidates stored per slice (expected ~3.2)
#define MAXC   (SLICES*SLOT) // 1056 candidate slots per image
#define IOU_T 0.7f

// ---------------- Kernel A: candidate detection ----------------
// Channel-sliced waves for perfect coalescing: wave w covers a 20-channel band
// (w0:5..24 (+s0 ch4), w1:25..44, w2:45..64, w3:64..83; ch64 overlap is
// idempotent under max). Lane l covers anchor-group slice*64+l, so every load
// is 64 lanes x 16B contiguous = one 1KB transaction, 20 unrolled per wave.
// Cross-wave max via LDS; wave 0 (holding s0 in regs) tests + appends.
// valid anchor: s0 > 0.1 && s0 >= max(s1..s79)
__global__ __launch_bounds__(256) void cand_kernel(const float* __restrict__ preds,
        int* __restrict__ counts, float* __restrict__ cscore, int* __restrict__ cidx) {
    int b = blockIdx.x / SLICES;
    int slice = blockIdx.x - b * SLICES;
    int t = threadIdx.x;
    int w = t >> 6, l = t & 63;
    int g = slice * 64 + l;              // anchor group 0..2099
    bool active = g < GROUPS;

    __shared__ int lcount;
    __shared__ float4 red[3][64];        // waves 1..3 partial maxes
    __shared__ float lsc[256];
    __shared__ int   lix[256];
    if (t == 0) lcount = 0;

    const float* base = preds + (size_t)b * (CH * NA);
    float mx = -1.f, my = -1.f, mz = -1.f, mw = -1.f;
    float4 s0 = make_float4(-2.f, -2.f, -2.f, -2.f);
    if (active) {
        int c0 = (w < 3) ? (5 + 20 * w) : 64;          // 5..24,25..44,45..64,64..83
        const float* p = base + (size_t)c0 * NA + 4 * g;
        #pragma unroll
        for (int k = 0; k < 20; ++k, p += NA) {
            float4 v = *(const float4*)p;
            mx = fmaxf(mx, v.x); my = fmaxf(my, v.y);
            mz = fmaxf(mz, v.z); mw = fmaxf(mw, v.w);
        }
        if (w == 0) s0 = *(const float4*)(base + (size_t)4 * NA + 4 * g);
    }
    if (w > 0) red[w - 1][l] = make_float4(mx, my, mz, mw);
    __syncthreads();

    if (w == 0 && active) {
        #pragma unroll
        for (int ww = 0; ww < 3; ++ww) {
            float4 r = red[ww][l];
            mx = fmaxf(mx, r.x); my = fmaxf(my, r.y);
            mz = fmaxf(mz, r.z); mw = fmaxf(mw, r.w);
        }
        float s[4] = {s0.x, s0.y, s0.z, s0.w};
        float m[4] = {mx, my, mz, mw};
        #pragma unroll
        for (int k = 0; k < 4; ++k) {
            if (s[k] > 0.1f && s[k] >= m[k]) {
                int p_ = atomicAdd(&lcount, 1);     // LDS atomic only
                lsc[p_] = s[k];
                lix[p_] = 4 * g + k;
            }
        }
    }
    __syncthreads();
    int n = lcount; if (n > SLOT) n = SLOT;
    if (t == 0) counts[b * SLICES + slice] = n;      // unconditional: poison-proof
    if (t < n) {
        cscore[b * MAXC + slice * SLOT + t] = lsc[t];
        cidx[b * MAXC + slice * SLOT + t]   = lix[t];
    }
}

// ---------------- wave-parallel greedy NMS scan ----------------
// One wave (64 lanes); lane owns candidates k*64+lane, k<S, boxes in NAMED regs
// (compile-time indexed -> no scratch). Suppressor i's keep bit via __ballot,
// its box via same-address LDS broadcast. Returns per-lane keep bitmask.
template<int S>
__device__ unsigned int nms_scan(int n, int lane, const float4* bxy, const float* ars) {
    float ox1[S], oy1[S], ox2[S], oy2[S], oar[S];
    unsigned int keep = 0u;
    #pragma unroll
    for (int k = 0; k < S; ++k) {
        int c = k * 64 + lane;
        if (c < n) {
            float4 v = bxy[c];
            ox1[k] = v.x; oy1[k] = v.y; ox2[k] = v.z; oy2[k] = v.w;
            oar[k] = ars[c];
            keep |= (1u << k);
        } else {
            ox1[k] = 0.f; oy1[k] = 0.f; ox2[k] = -1.f; oy2[k] = -1.f; oar[k] = 0.f;
        }
    }
    for (int i = 0; i < n; ++i) {
        int which = i >> 6, src = i & 63;
        int mybit = (keep >> which) & 1;
        unsigned long long bal = __ballot(mybit);
        if ((bal >> src) & 1ull) {          // uniform branch: is candidate i kept?
            float4 bi = bxy[i];             // LDS broadcast (same address all lanes)
            float ai = ars[i];
            #pragma unroll
            for (int k = 0; k < S; ++k) {
                float lx = fmaxf(bi.x, ox1[k]), ly = fmaxf(bi.y, oy1[k]);
                float rx = fminf(bi.z, ox2[k]), ry = fminf(bi.w, oy2[k]);
                float iw = fmaxf(rx - lx, 0.0f), ih = fmaxf(ry - ly, 0.0f);
                float inter = iw * ih;
                float iou = inter / (ai + oar[k] - inter + 1e-7f);
                int c = k * 64 + lane;
                if (c > i && iou > IOU_T) keep &= ~(1u << k);
            }
        }
    }
    return keep;
}

// ---------------- Kernel B: compact + sort + NMS + output ----------------
__global__ __launch_bounds__(256) void nms_kernel(const float* __restrict__ preds,
        const int* __restrict__ counts, const float* __restrict__ cscore,
        const int* __restrict__ cidx, float* __restrict__ out) {
    int b = blockIdx.x;
    int tid = threadIdx.x;

    __shared__ int scnt[SLICES], soff[SLICES + 1];
    __shared__ float rs[MAXC]; __shared__ int ri[MAXC];   // compacted raw candidates
    __shared__ float ss[MAXC]; __shared__ int sa[MAXC];   // sorted (score desc, idx asc)
    __shared__ float4 bxy[MAXC];                          // sorted boxes xyxy
    __shared__ float  ars[MAXC];                          // areas
    __shared__ unsigned int keepm[64];                    // per-lane keep bitmask

    if (tid < SLICES) scnt[tid] = counts[b * SLICES + tid];
    __syncthreads();
    if (tid == 0) {                                       // 33-entry prefix sum, trivial
        int acc = 0;
        #pragma unroll
        for (int s_ = 0; s_ < SLICES; ++s_) { soff[s_] = acc; acc += scnt[s_]; }
        soff[SLICES] = acc;
    }
    __syncthreads();
    int n = soff[SLICES];

    // compact per-slice slots into dense [0,n)
    for (int t = tid; t < SLICES * SLOT; t += 256) {
        int slice = t >> 5, j = t & (SLOT - 1);
        if (j < scnt[slice]) {
            int dst = soff[slice] + j;
            rs[dst] = cscore[b * MAXC + t];
            ri[dst] = cidx[b * MAXC + t];
        }
    }
    __syncthreads();

    // stable rank sort: rank = #{j : s_j > s_i || (s_j == s_i && idx_j < idx_i)}
    for (int i = tid; i < n; i += 256) {
        float si = rs[i]; int ii = ri[i];
        int r = 0;
        for (int j = 0; j < n; ++j) {
            float sj = rs[j]; int ij = ri[j];
            if (sj > si || (sj == si && ij < ii)) r++;
        }
        ss[r] = si; sa[r] = ii;
    }
    __syncthreads();

    // gather boxes, xywh -> xyxy
    const float* base = preds + (size_t)b * (CH * NA);
    for (int i = tid; i < n; i += 256) {
        int a = sa[i];
        float cx = base[a], cy = base[NA + a];
        float w  = base[2 * NA + a], h = base[3 * NA + a];
        float hx = w * 0.5f, hy = h * 0.5f;
        float X1 = cx - hx, Y1 = cy - hy, X2 = cx + hx, Y2 = cy + hy;
        bxy[i] = make_float4(X1, Y1, X2, Y2);
        ars[i] = (X2 - X1) * (Y2 - Y1);
    }
    __syncthreads();

    if (tid < 64) {
        unsigned int kp;
        if (n <= 128)      kp = nms_scan<2>(n, tid, bxy, ars);
        else if (n <= 256) kp = nms_scan<4>(n, tid, bxy, ars);
        else if (n <= 512) kp = nms_scan<8>(n, tid, bxy, ars);
        else               kp = nms_scan<17>(n, tid, bxy, ars);  // up to 1088 >= MAXC
        keepm[tid] = kp;
    }
    __syncthreads();

    // write all K rows (d_out is poisoned -> zeros must be written too)
    float* ob = out + (size_t)b * KTOP * 6;
    const float SCALEF = (float)(640.0 / 1920.0);
    for (int r = tid; r < KTOP; r += 256) {
        float v0 = 0.f, v1 = 0.f, v2 = 0.f, v3 = 0.f, v4 = 0.f, v5 = 0.f;
        if (r < n && ((keepm[r & 63] >> (r >> 6)) & 1u)) {
            float4 bx = bxy[r];
            v0 = bx.x / SCALEF; v1 = bx.y / SCALEF;
            v2 = bx.z / SCALEF; v3 = bx.w / SCALEF;
            v4 = ss[r]; v5 = 0.0f;
        }
        ob[r * 6 + 0] = v0; ob[r * 6 + 1] = v1; ob[r * 6 + 2] = v2;
        ob[r * 6 + 3] = v3; ob[r * 6 + 4] = v4; ob[r * 6 + 5] = v5;
    }
}

extern "C" void kernel_launch(void* const* d_in, const int* in_sizes, int n_in,
                              void* d_out, int out_size, void* d_ws, size_t ws_size,
                              hipStream_t stream) {
    const float* preds = (const float*)d_in[0];
    float* out = (float*)d_out;

    // ws layout (all read locations are written by cand_kernel first -> no memset)
    int*   counts = (int*)d_ws;                                   // 32*33 ints
    float* cscore = (float*)((char*)d_ws + 16384);                // 32*1056 floats
    int*   cidx   = (int*)((char*)d_ws + 16384 + (size_t)BATCH * MAXC * sizeof(float));

    cand_kernel<<<BATCH * SLICES, 256, 0, stream>>>(preds, counts, cscore, cidx);
    nms_kernel<<<BATCH, 256, 0, stream>>>(preds, counts, cscore, cidx, out);
}